// Round 1
// 395.119 us; speedup vs baseline: 1.0709x; 1.0709x over previous
//
#include <hip/hip_runtime.h>

// ShiftedWindowMSA fused kernel for MI355X (gfx950).
// Grid: 2048 blocks = (b, u, v) windows; 512 threads = 8 waves; wave = head everywhere.
// Head-local weight permutation: np = head*96 + t*32 + e, so wave w computes its own
// head's Q/K/V -> per-wave 4KB transpose scratch instead of 96KB shared sQ/sK/sVt.
// LDS 132KB -> 66KB => 2 blocks/CU (was 1): latency hiding via co-resident blocks.

typedef short bf16x8 __attribute__((ext_vector_type(8)));   // 8 bf16 in 4 VGPRs
typedef float f32x4 __attribute__((ext_vector_type(4)));
typedef unsigned short u16;
typedef u16 u16x8 __attribute__((ext_vector_type(8)));

#define MFMA16 __builtin_amdgcn_mfma_f32_16x16x32_bf16

__device__ __forceinline__ u16 f2bf(float f) {          // RNE fp32 -> bf16
  union { float f; unsigned int u; } c; c.f = f;
  unsigned int uu = c.u;
  return (u16)((uu + 0x7fffu + ((uu >> 16) & 1u)) >> 16);
}

// ---- LDS layout (bytes) ----
// T    per-wave scratch [8][4096]: 64x32 bf16 transpose buf (Q, then K, then Vt, then P)
//      layout rows: row*64 + chunk^swz, chunk=16B                         @ 0      (32 KB)
// sA   [64 rows][256 ch] bf16, 16B-chunk XOR swizzle (chunk ^= row&7)     @ 32768  (32 KB)
// sPos f32[169]                                                           @ 65536
#define OFF_A   32768
#define OFF_POS 65536
#define SMEM_BYTES (65536 + 704)

__global__ void prep_w(const float* __restrict__ w1, const float* __restrict__ b1,
                       u16* __restrict__ wT, float* __restrict__ bp) {
  // coalesced row-major read of w1[k][n]; scattered 2B writes land in L2 (wT = 384KB)
  int g = blockIdx.x * 256 + threadIdx.x;        // [0, 256*768)
  float val = w1[g];
  int n = g % 768;                               // original w1 column
  int k = g / 768;                               // k row
  int t = n % 3, c = n / 3;                      // c = eidx*8 + head
  int np = (c & 7) * 96 + t * 32 + (c >> 3);     // head-local permuted column
  wT[np * 256 + k] = f2bf(val);
  if (g < 768) {
    int t2 = g % 3, c2 = g / 3;
    bp[(c2 & 7) * 96 + t2 * 32 + (c2 >> 3)] = b1[g];
  }
}

__launch_bounds__(512, 4)
__global__ void swin_fused(const float* __restrict__ x, const u16* __restrict__ wT,
                           const float* __restrict__ bp, const float* __restrict__ pos,
                           float* __restrict__ out) {
  __shared__ __align__(16) char smem[SMEM_BYTES];
  const int tid  = threadIdx.x;
  const int wave = tid >> 6;
  const int lane = tid & 63;
  const int quad = lane >> 4;
  const int l16  = lane & 15;
  const int blk  = blockIdx.x;
  const int b = blk >> 6, u = (blk >> 3) & 7, v = blk & 7;

  float* sPos = (float*)(smem + OFF_POS);
  if (tid < 169) sPos[tid] = pos[tid];

  // ---------- phase 1: stage x window -> sA (bf16) ----------
  // roll(qkv, -4): window row h' reads x at (h'+4)%56 (note: -7//2 == -4 in Python!)
  {
    const int xbase = b * (56 * 56 * 256);
#pragma unroll
    for (int it = 0; it < 4; ++it) {
      int idx = tid + it * 512;                  // 64 rows * 32 chunks(8ch)
      int row = idx >> 5;
      int ck  = idx & 31;
      char* dst = smem + OFF_A + row * 512 + ((ck ^ (row & 7)) << 4);
      u16x8 val{};
      if (row < 49) {
        int i = row / 7, j = row % 7;
        int sh = u * 7 + i + 4; if (sh >= 56) sh -= 56;
        int sw = v * 7 + j + 4; if (sw >= 56) sw -= 56;
        const float4* src = (const float4*)(x + xbase + (sh * 56 + sw) * 256 + ck * 8);
        float4 f0 = src[0];
        float4 f1 = src[1];
        val.s0 = f2bf(f0.x); val.s1 = f2bf(f0.y); val.s2 = f2bf(f0.z); val.s3 = f2bf(f0.w);
        val.s4 = f2bf(f1.x); val.s5 = f2bf(f1.y); val.s6 = f2bf(f1.z); val.s7 = f2bf(f1.w);
      }
      *(u16x8*)dst = val;                        // rows 49..63 zeroed (keeps pads finite)
    }
  }

  // bias prefetch (L2-resident, per-lane; consumed in GEMM epilogues)
  float bias[6];
#pragma unroll
  for (int i = 0; i < 6; ++i) bias[i] = bp[wave * 96 + i * 16 + l16];

  __syncthreads();

  // ---------- phase 2: head-local QKV GEMM, 3 rounds (Q, K, V) ----------
  // round t: wave computes its head's 32 cols of {Q,K,V}[t] = [64x256]@[256x32]
  const char* sA = smem + OFF_A;
  char* T = smem + wave * 4096;                  // per-wave scratch
  bf16x8 qf[4], kf[4], vf[2][2];

#pragma unroll
  for (int t = 0; t < 3; ++t) {
    f32x4 acc[4][2];
#pragma unroll
    for (int m = 0; m < 4; ++m) {
      acc[m][0] = (f32x4){0.f, 0.f, 0.f, 0.f};
      acc[m][1] = (f32x4){0.f, 0.f, 0.f, 0.f};
    }
    const u16* gB0 = wT + (wave * 96 + t * 32 + l16) * 256 + quad * 8;
    const u16* gB1 = gB0 + 16 * 256;
    bf16x8 b0 = *(const bf16x8*)gB0;
    bf16x8 b1 = *(const bf16x8*)gB1;
#pragma unroll
    for (int ks = 0; ks < 8; ++ks) {
      bf16x8 a[4];
#pragma unroll
      for (int m = 0; m < 4; ++m) {
        int row = m * 16 + l16;
        a[m] = *(const bf16x8*)(sA + row * 512 + (((ks * 4 + quad) ^ (row & 7)) << 4));
      }
      bf16x8 b0n, b1n;
      if (ks < 7) {                              // register double-buffer for L2 B loads
        b0n = *(const bf16x8*)(gB0 + (ks + 1) * 32);
        b1n = *(const bf16x8*)(gB1 + (ks + 1) * 32);
      }
#pragma unroll
      for (int m = 0; m < 4; ++m) {
        acc[m][0] = MFMA16(a[m], b0, acc[m][0], 0, 0, 0);
        acc[m][1] = MFMA16(a[m], b1, acc[m][1], 0, 0, 0);
      }
      if (ks < 7) { b0 = b0n; b1 = b1n; }
    }

    // epilogue: +bias, per-wave transpose through T (C-layout row=quad*4+r, col=l16)
    if (t < 2) {
      // Q or K: T as [64 q][32 ch] bf16, chunk ^= row&3
#pragma unroll
      for (int m = 0; m < 4; ++m)
#pragma unroll
        for (int r = 0; r < 4; ++r) {
          int row = m * 16 + quad * 4 + r;
          int sw = row & 3;
          char* base = T + row * 64;
          *(u16*)(base + ((((l16 >> 3) ^ sw) << 4) | ((l16 & 7) << 1)))
              = f2bf(acc[m][0][r] + bias[t * 2]);          // ch = l16
          *(u16*)(base + (((((l16 >> 3) + 2) ^ sw) << 4) | ((l16 & 7) << 1)))
              = f2bf(acc[m][1][r] + bias[t * 2 + 1]);      // ch = 16+l16
        }
      asm volatile("s_waitcnt lgkmcnt(0)" ::: "memory");   // RAW: writes visible
#pragma unroll
      for (int m = 0; m < 4; ++m) {
        int row = m * 16 + l16;
        const bf16x8 fr = *(const bf16x8*)(T + row * 64 + ((quad ^ (row & 3)) << 4));
        if (t == 0) qf[m] = fr; else kf[m] = fr;
      }
      asm volatile("s_waitcnt lgkmcnt(0)" ::: "memory");   // WAR: reads done before reuse
    } else {
      // V: T as Vt[32 ch][64 key] bf16, chunk ^= ch&7
#pragma unroll
      for (int m = 0; m < 4; ++m)
#pragma unroll
        for (int r = 0; r < 4; ++r) {
          int key = m * 16 + quad * 4 + r;
          int kc = key >> 3, kb = (key & 7) << 1;
#pragma unroll
          for (int i = 0; i < 2; ++i) {
            int ch = i * 16 + l16;
            *(u16*)(T + ch * 128 + (((kc ^ (ch & 7)) << 4) | kb))
                = f2bf(acc[m][i][r] + bias[4 + i]);
          }
        }
      asm volatile("s_waitcnt lgkmcnt(0)" ::: "memory");
    }
  }

  // ---------- phase 3: attention (fully per-wave, no barriers) ----------
  {
    f32x4 s[4][4];
#pragma unroll
    for (int m = 0; m < 4; ++m)
#pragma unroll
      for (int n = 0; n < 4; ++n) s[m][n] = (f32x4){0.f, 0.f, 0.f, 0.f};
#pragma unroll
    for (int m = 0; m < 4; ++m)
#pragma unroll
      for (int n = 0; n < 4; ++n)
        s[m][n] = MFMA16(qf[m], kf[n], s[m][n], 0, 0, 0);  // S[q][k] = Q.K^T

    // V fragments -> registers (16 VGPRs) so T can be reused for P
#pragma unroll
    for (int ph = 0; ph < 2; ++ph)
#pragma unroll
      for (int n = 0; n < 2; ++n) {
        int ch = n * 16 + l16;
        vf[ph][n] = *(const bf16x8*)(T + ch * 128 + (((ph * 4 + quad) ^ (ch & 7)) << 4));
      }
    asm volatile("s_waitcnt lgkmcnt(0)" ::: "memory");     // vf landed before P overwrites T

    // scale + rel-pos bias + shift masks + softmax (in C-layout registers)
    const bool rowm = (u == 7), colm = (v == 7);
    int ki[4], kj[4]; bool kok[4], kro[4], kco[4];
#pragma unroll
    for (int n = 0; n < 4; ++n) {
      int k = n * 16 + l16;
      ki[n] = k / 7; kj[n] = k % 7;
      kok[n] = (k < 49);
      kro[n] = (ki[n] >= 4);
      kco[n] = (kj[n] >= 4);
    }
    const float scale = 0.17677669529663687f;    // 1/sqrt(32)
    float rsum[4][4];
#pragma unroll
    for (int m = 0; m < 4; ++m) {
#pragma unroll
      for (int r = 0; r < 4; ++r) {
        int q = m * 16 + quad * 4 + r;
        int qi = q / 7, qj = q % 7;
        bool qro = (qi >= 4), qco = (qj >= 4);
        float vmax = -3e30f;
#pragma unroll
        for (int n = 0; n < 4; ++n) {
          bool bad = (!kok[n]) || (rowm && (qro != kro[n])) || (colm && (qco != kco[n]));
          float sv = bad ? -1e30f
                         : s[m][n][r] * scale + sPos[(ki[n] - qi + 6) * 13 + (kj[n] - qj + 6)];
          s[m][n][r] = sv;
          vmax = fmaxf(vmax, sv);
        }
        vmax = fmaxf(vmax, __shfl_xor(vmax, 1));
        vmax = fmaxf(vmax, __shfl_xor(vmax, 2));
        vmax = fmaxf(vmax, __shfl_xor(vmax, 4));
        vmax = fmaxf(vmax, __shfl_xor(vmax, 8));
        float sum = 0.f;
#pragma unroll
        for (int n = 0; n < 4; ++n) {
          float p = __expf(s[m][n][r] - vmax);   // masked/pad keys -> exp(-1e30-m) = 0
          s[m][n][r] = p;
          sum += p;
        }
        sum += __shfl_xor(sum, 1);
        sum += __shfl_xor(sum, 2);
        sum += __shfl_xor(sum, 4);
        sum += __shfl_xor(sum, 8);
        rsum[m][r] = sum;
      }
    }

    // PV in two key-halves through T (P layout [64 q][32 key], chunk ^= row&3)
    f32x4 o[4][2];
#pragma unroll
    for (int m = 0; m < 4; ++m) { o[m][0] = (f32x4){0.f,0.f,0.f,0.f}; o[m][1] = (f32x4){0.f,0.f,0.f,0.f}; }

#pragma unroll
    for (int ph = 0; ph < 2; ++ph) {
#pragma unroll
      for (int n2 = 0; n2 < 2; ++n2) {
        int n  = ph * 2 + n2;
        int kh = n2 * 16 + l16;                  // key within half [0,32)
        int kb = (kh & 7) << 1;
#pragma unroll
        for (int m = 0; m < 4; ++m)
#pragma unroll
          for (int r = 0; r < 4; ++r) {
            int row = m * 16 + quad * 4 + r;
            *(u16*)(T + row * 64 + ((((kh >> 3) ^ (row & 3)) << 4) | kb)) = f2bf(s[m][n][r]);
          }
      }
      asm volatile("s_waitcnt lgkmcnt(0)" ::: "memory");   // RAW: P visible
      bf16x8 pa[4];
#pragma unroll
      for (int m = 0; m < 4; ++m) {
        int row = m * 16 + l16;
        pa[m] = *(const bf16x8*)(T + row * 64 + ((quad ^ (row & 3)) << 4));
      }
#pragma unroll
      for (int m = 0; m < 4; ++m)
#pragma unroll
        for (int n = 0; n < 2; ++n)
          o[m][n] = MFMA16(pa[m], vf[ph][n], o[m][n], 0, 0, 0);
    }

    // output: roll-back is +3 (NOT +4); channel c = eidx*8 + head
    const int hh = wave;
#pragma unroll
    for (int m = 0; m < 4; ++m)
#pragma unroll
      for (int r = 0; r < 4; ++r) {
        int row = m * 16 + quad * 4 + r;
        if (row < 49) {
          int i = row / 7, j = row % 7;
          int dh = u * 7 + i + 3; if (dh >= 56) dh -= 56;
          int dw = v * 7 + j + 3; if (dw >= 56) dw -= 56;
          float inv = 1.f / rsum[m][r];
          float* op = out + ((b * 56 + dh) * 56 + dw) * 256 + hh;
          op[l16 * 8]         = o[m][0][r] * inv;
          op[(16 + l16) * 8]  = o[m][1][r] * inv;
        }
      }
  }
}

extern "C" void kernel_launch(void* const* d_in, const int* in_sizes, int n_in,
                              void* d_out, int out_size, void* d_ws, size_t ws_size,
                              hipStream_t stream) {
  const float* x   = (const float*)d_in[0];
  const float* w1  = (const float*)d_in[1];
  const float* b1  = (const float*)d_in[2];
  const float* pos = (const float*)d_in[3];
  const size_t need = (size_t)768 * 256 * 2 + 768 * 4;
  if (ws_size < need) return;                    // visible failure instead of corruption
  u16*   wT = (u16*)d_ws;
  float* bp = (float*)((char*)d_ws + 768 * 256 * 2);
  prep_w<<<768, 256, 0, stream>>>(w1, b1, wT, bp);
  swin_fused<<<2048, 512, 0, stream>>>(x, wT, bp, pos, (float*)d_out);
}

// Round 2
// 342.661 us; speedup vs baseline: 1.2348x; 1.1531x over previous
//
#include <hip/hip_runtime.h>

// ShiftedWindowMSA fused kernel for MI355X (gfx950).
// Grid: 2048 blocks = (b, u, v) windows; 512 threads = 8 waves; wave = head everywhere.
// Head-local weight permutation: np = head*96 + t*32 + e, so wave w computes its own
// head's Q/K/V -> per-wave 4KB transpose scratch instead of 96KB shared sQ/sK/sVt.
// Output is staged in LDS (f32) and stored coalesced (dwordx4, full lines): avoids the
// 4x HBM write amplification + RFO fetches of per-lane scattered 4B stores.

typedef short bf16x8 __attribute__((ext_vector_type(8)));   // 8 bf16 in 4 VGPRs
typedef float f32x4 __attribute__((ext_vector_type(4)));
typedef unsigned short u16;
typedef u16 u16x8 __attribute__((ext_vector_type(8)));

#define MFMA16 __builtin_amdgcn_mfma_f32_16x16x32_bf16

__device__ __forceinline__ u16 f2bf(float f) {          // RNE fp32 -> bf16
  union { float f; unsigned int u; } c; c.f = f;
  unsigned int uu = c.u;
  return (u16)((uu + 0x7fffu + ((uu >> 16) & 1u)) >> 16);
}

// ---- LDS layout (bytes) ----
// T    per-wave scratch [8][4096]: 64x32 bf16 transpose buf (Q, then K, then Vt, then P)
//      swizzles use (row>>2)&3 so the XOR varies across the lanes of one store instr
// sA   [64 rows][256 ch] bf16, 16B-chunk XOR swizzle (chunk ^= row&7)     @ 32768  (32 KB)
// oLds f32 [49 rows][260 f32] (row stride 1040B), reuses T+sA after attention (51 KB)
// sPos f32[169]                                                           @ 65536
#define OFF_A   32768
#define OFF_POS 65536
#define SMEM_BYTES (65536 + 704)

__global__ void prep_w(const float* __restrict__ w1, const float* __restrict__ b1,
                       u16* __restrict__ wT, float* __restrict__ bp) {
  // coalesced row-major read of w1[k][n]; scattered 2B writes land in L2 (wT = 384KB)
  int g = blockIdx.x * 256 + threadIdx.x;        // [0, 256*768)
  float val = w1[g];
  int n = g % 768;                               // original w1 column
  int k = g / 768;                               // k row
  int t = n % 3, c = n / 3;                      // c = eidx*8 + head
  int np = (c & 7) * 96 + t * 32 + (c >> 3);     // head-local permuted column
  wT[np * 256 + k] = f2bf(val);
  if (g < 768) {
    int t2 = g % 3, c2 = g / 3;
    bp[(c2 & 7) * 96 + t2 * 32 + (c2 >> 3)] = b1[g];
  }
}

__launch_bounds__(512, 4)
__global__ void swin_fused(const float* __restrict__ x, const u16* __restrict__ wT,
                           const float* __restrict__ bp, const float* __restrict__ pos,
                           float* __restrict__ out) {
  __shared__ __align__(16) char smem[SMEM_BYTES];
  const int tid  = threadIdx.x;
  const int wave = tid >> 6;
  const int lane = tid & 63;
  const int quad = lane >> 4;
  const int l16  = lane & 15;
  const int blk  = blockIdx.x;
  const int b = blk >> 6, u = (blk >> 3) & 7, v = blk & 7;

  float* sPos = (float*)(smem + OFF_POS);
  if (tid < 169) sPos[tid] = pos[tid];

  // ---------- phase 1: stage x window -> sA (bf16) ----------
  // roll(qkv, -4): window row h' reads x at (h'+4)%56 (note: -7//2 == -4 in Python!)
  {
    const int xbase = b * (56 * 56 * 256);
#pragma unroll
    for (int it = 0; it < 4; ++it) {
      int idx = tid + it * 512;                  // 64 rows * 32 chunks(8ch)
      int row = idx >> 5;
      int ck  = idx & 31;
      char* dst = smem + OFF_A + row * 512 + ((ck ^ (row & 7)) << 4);
      u16x8 val{};
      if (row < 49) {
        int i = row / 7, j = row % 7;
        int sh = u * 7 + i + 4; if (sh >= 56) sh -= 56;
        int sw = v * 7 + j + 4; if (sw >= 56) sw -= 56;
        const float4* src = (const float4*)(x + xbase + (sh * 56 + sw) * 256 + ck * 8);
        float4 f0 = src[0];
        float4 f1 = src[1];
        val.s0 = f2bf(f0.x); val.s1 = f2bf(f0.y); val.s2 = f2bf(f0.z); val.s3 = f2bf(f0.w);
        val.s4 = f2bf(f1.x); val.s5 = f2bf(f1.y); val.s6 = f2bf(f1.z); val.s7 = f2bf(f1.w);
      }
      *(u16x8*)dst = val;                        // rows 49..63 zeroed (keeps pads finite)
    }
  }

  // bias prefetch (L2-resident, per-lane; consumed in GEMM epilogues)
  float bias[6];
#pragma unroll
  for (int i = 0; i < 6; ++i) bias[i] = bp[wave * 96 + i * 16 + l16];

  __syncthreads();

  // ---------- phase 2: head-local QKV GEMM, 3 rounds (Q, K, V) ----------
  // round t: wave computes its head's 32 cols of {Q,K,V}[t] = [64x256]@[256x32]
  const char* sA = smem + OFF_A;
  char* T = smem + wave * 4096;                  // per-wave scratch
  bf16x8 qf[4], kf[4], vf[2][2];

#pragma unroll
  for (int t = 0; t < 3; ++t) {
    f32x4 acc[4][2];
#pragma unroll
    for (int m = 0; m < 4; ++m) {
      acc[m][0] = (f32x4){0.f, 0.f, 0.f, 0.f};
      acc[m][1] = (f32x4){0.f, 0.f, 0.f, 0.f};
    }
    const u16* gB0 = wT + (wave * 96 + t * 32 + l16) * 256 + quad * 8;
    const u16* gB1 = gB0 + 16 * 256;
    bf16x8 b0 = *(const bf16x8*)gB0;
    bf16x8 b1 = *(const bf16x8*)gB1;
#pragma unroll
    for (int ks = 0; ks < 8; ++ks) {
      bf16x8 a[4];
#pragma unroll
      for (int m = 0; m < 4; ++m) {
        int row = m * 16 + l16;
        a[m] = *(const bf16x8*)(sA + row * 512 + (((ks * 4 + quad) ^ (row & 7)) << 4));
      }
      bf16x8 b0n, b1n;
      if (ks < 7) {                              // register double-buffer for L2 B loads
        b0n = *(const bf16x8*)(gB0 + (ks + 1) * 32);
        b1n = *(const bf16x8*)(gB1 + (ks + 1) * 32);
      }
#pragma unroll
      for (int m = 0; m < 4; ++m) {
        acc[m][0] = MFMA16(a[m], b0, acc[m][0], 0, 0, 0);
        acc[m][1] = MFMA16(a[m], b1, acc[m][1], 0, 0, 0);
      }
      if (ks < 7) { b0 = b0n; b1 = b1n; }
    }

    // epilogue: +bias, per-wave transpose through T (C-layout row=quad*4+r, col=l16)
    if (t < 2) {
      // Q or K: T as [64 q][32 ch] bf16, chunk ^= (row>>2)&3 (varies per-instr -> ~4-way)
#pragma unroll
      for (int m = 0; m < 4; ++m)
#pragma unroll
        for (int r = 0; r < 4; ++r) {
          int row = m * 16 + quad * 4 + r;
          int sw = (row >> 2) & 3;
          char* base = T + row * 64;
          *(u16*)(base + ((((l16 >> 3) ^ sw) << 4) | ((l16 & 7) << 1)))
              = f2bf(acc[m][0][r] + bias[t * 2]);          // ch = l16
          *(u16*)(base + (((((l16 >> 3) + 2) ^ sw) << 4) | ((l16 & 7) << 1)))
              = f2bf(acc[m][1][r] + bias[t * 2 + 1]);      // ch = 16+l16
        }
      asm volatile("s_waitcnt lgkmcnt(0)" ::: "memory");   // RAW: writes visible
#pragma unroll
      for (int m = 0; m < 4; ++m) {
        int row = m * 16 + l16;
        const bf16x8 fr = *(const bf16x8*)(T + row * 64 + ((quad ^ ((row >> 2) & 3)) << 4));
        if (t == 0) qf[m] = fr; else kf[m] = fr;
      }
      asm volatile("s_waitcnt lgkmcnt(0)" ::: "memory");   // WAR: reads done before reuse
    } else {
      // V: T as Vt[32 ch][64 key] bf16, chunk ^= ch&7
#pragma unroll
      for (int m = 0; m < 4; ++m)
#pragma unroll
        for (int r = 0; r < 4; ++r) {
          int key = m * 16 + quad * 4 + r;
          int kc = key >> 3, kb = (key & 7) << 1;
#pragma unroll
          for (int i = 0; i < 2; ++i) {
            int ch = i * 16 + l16;
            *(u16*)(T + ch * 128 + (((kc ^ (ch & 7)) << 4) | kb))
                = f2bf(acc[m][i][r] + bias[4 + i]);
          }
        }
      asm volatile("s_waitcnt lgkmcnt(0)" ::: "memory");
    }
  }

  // ---------- phase 3: attention (fully per-wave, no barriers) ----------
  float rsum[4][4];
  f32x4 o[4][2];
  {
    f32x4 s[4][4];
#pragma unroll
    for (int m = 0; m < 4; ++m)
#pragma unroll
      for (int n = 0; n < 4; ++n) s[m][n] = (f32x4){0.f, 0.f, 0.f, 0.f};
#pragma unroll
    for (int m = 0; m < 4; ++m)
#pragma unroll
      for (int n = 0; n < 4; ++n)
        s[m][n] = MFMA16(qf[m], kf[n], s[m][n], 0, 0, 0);  // S[q][k] = Q.K^T

    // V fragments -> registers (16 VGPRs) so T can be reused for P
#pragma unroll
    for (int ph = 0; ph < 2; ++ph)
#pragma unroll
      for (int n = 0; n < 2; ++n) {
        int ch = n * 16 + l16;
        vf[ph][n] = *(const bf16x8*)(T + ch * 128 + (((ph * 4 + quad) ^ (ch & 7)) << 4));
      }
    asm volatile("s_waitcnt lgkmcnt(0)" ::: "memory");     // vf landed before P overwrites T

    // scale + rel-pos bias + shift masks + softmax (in C-layout registers)
    const bool rowm = (u == 7), colm = (v == 7);
    int ki[4], kj[4]; bool kok[4], kro[4], kco[4];
#pragma unroll
    for (int n = 0; n < 4; ++n) {
      int k = n * 16 + l16;
      ki[n] = k / 7; kj[n] = k % 7;
      kok[n] = (k < 49);
      kro[n] = (ki[n] >= 4);
      kco[n] = (kj[n] >= 4);
    }
    const float scale = 0.17677669529663687f;    // 1/sqrt(32)
#pragma unroll
    for (int m = 0; m < 4; ++m) {
#pragma unroll
      for (int r = 0; r < 4; ++r) {
        int q = m * 16 + quad * 4 + r;
        int qi = q / 7, qj = q % 7;
        bool qro = (qi >= 4), qco = (qj >= 4);
        float vmax = -3e30f;
#pragma unroll
        for (int n = 0; n < 4; ++n) {
          bool bad = (!kok[n]) || (rowm && (qro != kro[n])) || (colm && (qco != kco[n]));
          float sv = bad ? -1e30f
                         : s[m][n][r] * scale + sPos[(ki[n] - qi + 6) * 13 + (kj[n] - qj + 6)];
          s[m][n][r] = sv;
          vmax = fmaxf(vmax, sv);
        }
        vmax = fmaxf(vmax, __shfl_xor(vmax, 1));
        vmax = fmaxf(vmax, __shfl_xor(vmax, 2));
        vmax = fmaxf(vmax, __shfl_xor(vmax, 4));
        vmax = fmaxf(vmax, __shfl_xor(vmax, 8));
        float sum = 0.f;
#pragma unroll
        for (int n = 0; n < 4; ++n) {
          float p = __expf(s[m][n][r] - vmax);   // masked/pad keys -> exp(-1e30-m) = 0
          s[m][n][r] = p;
          sum += p;
        }
        sum += __shfl_xor(sum, 1);
        sum += __shfl_xor(sum, 2);
        sum += __shfl_xor(sum, 4);
        sum += __shfl_xor(sum, 8);
        rsum[m][r] = sum;
      }
    }

    // PV in two key-halves through T (P layout [64 q][32 key], chunk ^= (row>>2)&3)
#pragma unroll
    for (int m = 0; m < 4; ++m) { o[m][0] = (f32x4){0.f,0.f,0.f,0.f}; o[m][1] = (f32x4){0.f,0.f,0.f,0.f}; }

#pragma unroll
    for (int ph = 0; ph < 2; ++ph) {
#pragma unroll
      for (int n2 = 0; n2 < 2; ++n2) {
        int n  = ph * 2 + n2;
        int kh = n2 * 16 + l16;                  // key within half [0,32)
        int kb = (kh & 7) << 1;
#pragma unroll
        for (int m = 0; m < 4; ++m)
#pragma unroll
          for (int r = 0; r < 4; ++r) {
            int row = m * 16 + quad * 4 + r;
            *(u16*)(T + row * 64 + ((((kh >> 3) ^ ((row >> 2) & 3)) << 4) | kb)) = f2bf(s[m][n][r]);
          }
      }
      asm volatile("s_waitcnt lgkmcnt(0)" ::: "memory");   // RAW: P visible
      bf16x8 pa[4];
#pragma unroll
      for (int m = 0; m < 4; ++m) {
        int row = m * 16 + l16;
        pa[m] = *(const bf16x8*)(T + row * 64 + ((quad ^ ((row >> 2) & 3)) << 4));
      }
#pragma unroll
      for (int m = 0; m < 4; ++m)
#pragma unroll
        for (int n = 0; n < 2; ++n)
          o[m][n] = MFMA16(pa[m], vf[ph][n], o[m][n], 0, 0, 0);
    }
  }

  // ---------- phase 4: deposit o into LDS (f32), then coalesced store ----------
  __syncthreads();                               // all waves done with T/sA
  {
    float* oLds = (float*)smem;                  // [49 rows][260 f32], stride 1040B
    const int hh = wave;
#pragma unroll
    for (int m = 0; m < 4; ++m)
#pragma unroll
      for (int r = 0; r < 4; ++r) {
        int row = m * 16 + quad * 4 + r;
        if (row < 49) {
          float inv = 1.f / rsum[m][r];
#pragma unroll
          for (int n = 0; n < 2; ++n) {
            int ci = n * 32 + l16 * 2 + (hh >> 2);       // 16B-chunk index of ch = n*128+l16*8+hh
            int cs = ci ^ ((ci >> 3) & 3);               // XOR swizzle (bijective per row)
            oLds[row * 260 + cs * 4 + (hh & 3)] = o[m][n][r] * inv;
          }
        }
      }
  }
  __syncthreads();
  {
    // 49 rows x 1024B, one wave per row per iteration: full-line dwordx4 stores
    const int obase = b * (56 * 56 * 256);
    for (int i = tid; i < 49 * 64; i += 512) {
      int row = i >> 6, ck = i & 63;
      int ii = row / 7, jj = row % 7;
      int dh = u * 7 + ii + 3; if (dh >= 56) dh -= 56;   // roll-back is +3 (NOT +4)
      int dw = v * 7 + jj + 3; if (dw >= 56) dw -= 56;
      f32x4 val = *(const f32x4*)((const float*)smem + row * 260 + 4 * (ck ^ ((ck >> 3) & 3)));
      *(f32x4*)(out + obase + (dh * 56 + dw) * 256 + ck * 4) = val;
    }
  }
}

extern "C" void kernel_launch(void* const* d_in, const int* in_sizes, int n_in,
                              void* d_out, int out_size, void* d_ws, size_t ws_size,
                              hipStream_t stream) {
  const float* x   = (const float*)d_in[0];
  const float* w1  = (const float*)d_in[1];
  const float* b1  = (const float*)d_in[2];
  const float* pos = (const float*)d_in[3];
  const size_t need = (size_t)768 * 256 * 2 + 768 * 4;
  if (ws_size < need) return;                    // visible failure instead of corruption
  u16*   wT = (u16*)d_ws;
  float* bp = (float*)((char*)d_ws + 768 * 256 * 2);
  prep_w<<<768, 256, 0, stream>>>(w1, b1, wT, bp);
  swin_fused<<<2048, 512, 0, stream>>>(x, wT, bp, pos, (float*)d_out);
}